// Round 7
// baseline (308.802 us; speedup 1.0000x reference)
//
#include <hip/hip_runtime.h>
#include <stdint.h>

#define B 4
#define T 256
#define V 1024
#define S 64
#define DIM 1024
#define CV 256
#define NBLK 256

typedef __attribute__((ext_vector_type(8))) short bf16x8;
typedef __attribute__((ext_vector_type(4))) short s16x4;
typedef __attribute__((ext_vector_type(4))) float f32x4;

// ---- workspace layout (4-byte word offsets; bf16 arrays counted in words) ----
enum : int {
    WKT_O   = 0,                  // [262144 w] WkT bf16 [DIM][DIM] (d-major)
    WVT_O   = WKT_O + 262144,     // [262144 w] WvT bf16 [DIM][DIM]
    WUB_O   = WVT_O + 262144,     // [131072 w] Wu bf16 [CV][DIM]
    WKPB_O  = WUB_O + 131072,     // [131072 w] Wkp bf16 [CV][DIM]   (B^T for z)
    WVPT_O  = WKPB_O + 131072,    // [131072 w] WvpT bf16 [DIM][CV]  (B^T for out)
    XB_O    = WVPT_O + 131072,    // [262144 w] x bf16 [B*T][DIM]
    ZB_O    = XB_O + 262144,      // [131072 w] Z bf16 [B*T][CV]
    VB_O    = ZB_O + 131072,      // [524288 w] vision bf16 [B][V][CV]
    WB_O    = VB_O + 524288,      // [131072 w] W bf16 [B*T][CV]
    C0_O    = WB_O + 131072,      // [B*T] f32 bk.x
    RS_O    = C0_O + B*T,         // [B*T] f32 row sums
    PIDX_O  = RS_O + B*T,         // [B*T*S] int selected v
    BK_O    = PIDX_O + B*T*S,     // [DIM] f32 bu@Wk  (zeroed, atomic target)
    BV_O    = BK_O + DIM,         // [DIM] f32 bu@Wv  (zeroed, atomic target)
    DENOM_O = BV_O + DIM,         // [B]   f32        (zeroed, atomic target)
    BAR_O   = DENOM_O + B,        // [1] barrier arrive counter (zeroed)
    GEN_O   = BAR_O + 1,          // [1] barrier generation     (zeroed)
    WS_TOTAL= GEN_O + 1
};

__device__ __forceinline__ short f2bf(float f) {
    union { float f; unsigned u; } x; x.f = f;
    unsigned r = (x.u + 0x7FFF + ((x.u >> 16) & 1)) >> 16;
    return (short)r;
}
__device__ __forceinline__ float bf2f(short s) {
    union { unsigned u; float f; } x;
    x.u = ((unsigned)(unsigned short)s) << 16;
    return x.f;
}
__device__ __forceinline__ s16x4 cvt4(float4 f) {
    s16x4 o;
    o.x = f2bf(f.x); o.y = f2bf(f.y); o.z = f2bf(f.z); o.w = f2bf(f.w);
    return o;
}

// ---- grid barrier: generation-counted, agent-scope (cross-XCD safe) ----
__device__ __forceinline__ void gbar(int* __restrict__ bar, int* __restrict__ gen) {
    __syncthreads();                       // drain block's vmcnt/lgkmcnt
    if (threadIdx.x == 0) {
        int g = __hip_atomic_load(gen, __ATOMIC_RELAXED, __HIP_MEMORY_SCOPE_AGENT);
        int old = __hip_atomic_fetch_add(bar, 1, __ATOMIC_ACQ_REL,
                                         __HIP_MEMORY_SCOPE_AGENT);
        if (old == NBLK - 1) {
            __hip_atomic_store(bar, 0, __ATOMIC_RELAXED, __HIP_MEMORY_SCOPE_AGENT);
            __hip_atomic_fetch_add(gen, 1, __ATOMIC_RELEASE,
                                   __HIP_MEMORY_SCOPE_AGENT);
        } else {
            while (__hip_atomic_load(gen, __ATOMIC_ACQUIRE,
                                     __HIP_MEMORY_SCOPE_AGENT) == g)
                __builtin_amdgcn_s_sleep(1);
        }
    }
    __syncthreads();
}

// ---- per-wave 32x32 MFMA tile: A[m][k] row-major, Bt[n][k] row-major ----
template<int K, int LDA, int LDB>
__device__ __forceinline__ void wave_mma(const short* __restrict__ A0,
                                         const short* __restrict__ B0,
                                         f32x4 acc[2][2]) {
    int lane = threadIdx.x & 63;
    int rw = lane & 15, q = lane >> 4;
    const short* ap0 = A0 + rw * LDA + q * 8;
    const short* ap1 = ap0 + 16 * LDA;
    const short* bp0 = B0 + rw * LDB + q * 8;
    const short* bp1 = bp0 + 16 * LDB;
#pragma unroll 4
    for (int kc = 0; kc < K; kc += 32) {
        bf16x8 a0 = *(const bf16x8*)(ap0 + kc);
        bf16x8 a1 = *(const bf16x8*)(ap1 + kc);
        bf16x8 b0 = *(const bf16x8*)(bp0 + kc);
        bf16x8 b1 = *(const bf16x8*)(bp1 + kc);
        acc[0][0] = __builtin_amdgcn_mfma_f32_16x16x32_bf16(a0, b0, acc[0][0], 0, 0, 0);
        acc[0][1] = __builtin_amdgcn_mfma_f32_16x16x32_bf16(a0, b1, acc[0][1], 0, 0, 0);
        acc[1][0] = __builtin_amdgcn_mfma_f32_16x16x32_bf16(a1, b0, acc[1][0], 0, 0, 0);
        acc[1][1] = __builtin_amdgcn_mfma_f32_16x16x32_bf16(a1, b1, acc[1][1], 0, 0, 0);
    }
}

__global__ __launch_bounds__(256, 2)
void mega(const float* __restrict__ x, const float* __restrict__ vision,
          const void* __restrict__ maskp, const float* __restrict__ Wu,
          const float* __restrict__ bu, const float* __restrict__ Wk,
          const float* __restrict__ Wv, float* __restrict__ ws,
          int* __restrict__ wsi, float* __restrict__ out) {
    __shared__ short tlds[64 * 65];
    __shared__ float tred[4 * 64];
    __shared__ int mc_cnt[16][17];
    __shared__ int sa_flag, sb_flag;
    __shared__ int s_idx[4][64];
    __shared__ float s_ps[4][64];

    int tid = threadIdx.x;
    int lane = tid & 63, wv = tid >> 6;
    int gw = blockIdx.x * 4 + wv;          // global wave id, 0..1023
    int* bar = wsi + BAR_O;
    int* gen = wsi + GEN_O;

    // ================= phase A: converts + transpose/bias + mask ===============
    {
        int gtid = blockIdx.x * 256 + tid;   // 0..65535
        // vision f32 -> bf16 (262144 float4)
        {
            const float4* src = (const float4*)vision;
            s16x4* dst = (s16x4*)((short*)(ws + VB_O));
#pragma unroll
            for (int it = 0; it < 4; it++) {
                int i = it * 65536 + gtid;
                dst[i] = cvt4(src[i]);
            }
        }
        // Wu (65536 float4)
        {
            const float4* src = (const float4*)Wu;
            s16x4* dst = (s16x4*)((short*)(ws + WUB_O));
            dst[gtid] = cvt4(src[gtid]);
        }
        // x (262144 float4)
        {
            const float4* src = (const float4*)x;
            s16x4* dst = (s16x4*)((short*)(ws + XB_O));
#pragma unroll
            for (int it = 0; it < 4; it++) {
                int i = it * 65536 + gtid;
                dst[i] = cvt4(src[i]);
            }
        }
        // Wk/Wv transpose-convert + fused bias partials: 2 tiles per block
        for (int tt = 0; tt < 2; tt++) {
            int tile = blockIdx.x * 2 + tt;
            int which = tile >> 8, t2 = tile & 255;
            int e0 = (t2 >> 4) * 64, d0 = (t2 & 15) * 64;
            const float* src = which ? Wv : Wk;
            short* dst = (short*)(ws + (which ? WVT_O : WKT_O));
            int j = tid & 63, i0 = tid >> 6;
            float pb = 0.f;
#pragma unroll
            for (int p = 0; p < 16; p++) {
                int i = p * 4 + i0;
                float v = src[(size_t)(e0 + i) * DIM + d0 + j];
                tlds[j * 65 + i] = f2bf(v);
                pb += bu[e0 + i] * v;
            }
            tred[i0 * 64 + j] = pb;
            __syncthreads();
#pragma unroll
            for (int p = 0; p < 16; p++) {
                int dd = p * 4 + i0;
                dst[(size_t)(d0 + dd) * DIM + e0 + j] = tlds[dd * 65 + j];
            }
            if (i0 == 0) {
                float s = tred[j] + tred[64 + j] + tred[128 + j] + tred[192 + j];
                atomicAdd(ws + (which ? BV_O : BK_O) + d0 + j, s);
            }
            __syncthreads();
        }
        // mask compaction: blocks 0..63, single pass via 64-bit bitmask
        if (blockIdx.x < 64) {
            {   // block-local encoding detection over first 4 KB
                int a = 0, bfl = 0;
                const uchar4* m4 = (const uchar4*)maskp;
#pragma unroll
                for (int jj = 0; jj < 4; jj++) {
                    uchar4 u = m4[tid * 4 + jj];
                    if (u.y | u.z | u.w) a = 1;
                    if (u.x == 0x3f || u.y == 0x3f || u.z == 0x3f || u.w == 0x3f)
                        bfl = 1;
                }
                if (tid == 0) { sa_flag = 0; sb_flag = 0; }
                __syncthreads();
                if (a) sa_flag = 1;
                if (bfl) sb_flag = 1;
                __syncthreads();
            }
            bool byteMode = sa_flag && !sb_flag;
            int b = blockIdx.x >> 4, tg = blockIdx.x & 15;
            int tl = tid & 15, c = tid >> 4;
            int t = tg * 16 + tl;
            int v0 = c * 64;
            unsigned long long bits = 0ull;
            if (byteMode) {
                const uint8_t* m = (const uint8_t*)maskp + (size_t)(b * V + v0) * T + t;
#pragma unroll 8
                for (int j = 0; j < 64; j++)
                    if (m[(size_t)j * T] != 0) bits |= 1ull << j;
            } else {
                const int* m = (const int*)maskp + (size_t)(b * V + v0) * T + t;
#pragma unroll 8
                for (int j = 0; j < 64; j++)
                    if (m[(size_t)j * T] != 0) bits |= 1ull << j;
            }
            mc_cnt[tl][c] = __popcll(bits);
            __syncthreads();
            int off = 0, total = 0;
#pragma unroll
            for (int cc = 0; cc < 16; cc++) {
                int cn = mc_cnt[tl][cc];
                if (cc < c) off += cn;
                total += cn;
            }
            int base = PIDX_O + (b * T + t) * S;
            while (bits) {
                int j = __ffsll(bits) - 1;
                bits &= bits - 1;
                if (off < S) wsi[base + off] = v0 + j;
                off++;
            }
            if (c == 15)
                for (int j = (total < S ? total : S); j < S; j++) wsi[base + j] = 0;
        }
    }
    gbar(bar, gen);

    // ======= phase B: Wkp/WvpT prep GEMMs (waves 0..511) + c0 (waves 512+) =====
    if (gw < 512) {
        int which = gw >> 8, rem = gw & 255;
        int m0 = (rem >> 5) * 32, n0 = (rem & 31) * 32;
        const short* A = (const short*)(ws + WUB_O) + (size_t)m0 * DIM;
        const short* Bt = (const short*)(ws + (which ? WVT_O : WKT_O)) +
                          (size_t)n0 * DIM;
        f32x4 acc[2][2] = {};
        wave_mma<DIM, DIM, DIM>(A, Bt, acc);
        int col = lane & 15, q = lane >> 4;
        if (which == 0) {
            short* o = (short*)(ws + WKPB_O);
#pragma unroll
            for (int i = 0; i < 2; i++)
#pragma unroll
                for (int j = 0; j < 2; j++)
#pragma unroll
                    for (int r = 0; r < 4; r++)
                        o[(size_t)(m0 + i * 16 + q * 4 + r) * DIM +
                          n0 + j * 16 + col] = f2bf(acc[i][j][r]);
        } else {
            short* o = (short*)(ws + WVPT_O);
#pragma unroll
            for (int i = 0; i < 2; i++)
#pragma unroll
                for (int j = 0; j < 2; j++) {
                    s16x4 v;
                    v.x = f2bf(acc[i][j][0]); v.y = f2bf(acc[i][j][1]);
                    v.z = f2bf(acc[i][j][2]); v.w = f2bf(acc[i][j][3]);
                    *(s16x4*)&o[(size_t)(n0 + j * 16 + col) * CV +
                                m0 + i * 16 + q * 4] = v;
                }
        }
    } else {
        // c0[bt] = xb[bt] . bk, 2 bt per wave
#pragma unroll
        for (int rep = 0; rep < 2; rep++) {
            int bt = (gw - 512) * 2 + rep;
            const short* xr = (const short*)(ws + XB_O) + (size_t)bt * DIM;
            float a = 0.f;
#pragma unroll
            for (int jj = 0; jj < 4; jj++) {
                s16x4 xv = *(const s16x4*)(xr + jj * 256 + lane * 4);
                float4 k4 = *(const float4*)(ws + BK_O + jj * 256 + lane * 4);
                a += bf2f(xv.x) * k4.x + bf2f(xv.y) * k4.y +
                     bf2f(xv.z) * k4.z + bf2f(xv.w) * k4.w;
            }
            for (int o = 32; o > 0; o >>= 1) a += __shfl_xor(a, o);
            if (lane == 0) ws[C0_O + bt] = a;
        }
    }
    gbar(bar, gen);

    // ================= phase C: Z bf16 = Xb @ Wkp^T (waves 0..255) =============
    if (gw < 256) {
        int m0 = (gw >> 3) * 32, n0 = (gw & 7) * 32;
        const short* A = (const short*)(ws + XB_O) + (size_t)m0 * DIM;
        const short* Bt = (const short*)(ws + WKPB_O) + (size_t)n0 * DIM;
        f32x4 acc[2][2] = {};
        wave_mma<DIM, DIM, DIM>(A, Bt, acc);
        int col = lane & 15, q = lane >> 4;
        short* zb = (short*)(ws + ZB_O);
#pragma unroll
        for (int i = 0; i < 2; i++)
#pragma unroll
            for (int j = 0; j < 2; j++)
#pragma unroll
                for (int r = 0; r < 4; r++)
                    zb[(size_t)(m0 + i * 16 + q * 4 + r) * CV +
                       n0 + j * 16 + col] = f2bf(acc[i][j][r]);
    }
    gbar(bar, gen);

    // ================= phase D: attention per bt (wave = bt) ===================
    {
        int bt = gw, b = bt >> 8;
        s_idx[wv][lane] = wsi[PIDX_O + bt * S + lane];
        float c0 = ws[C0_O + bt];
        __syncthreads();
        int rw = lane & 15, q = lane >> 4;
        const short* vb = (const short*)(ws + VB_O) + (size_t)b * V * CV;
        const short* zp = (const short*)(ws + ZB_O) + (size_t)bt * CV + q * 8;
        f32x4 acc[4] = {};
#pragma unroll
        for (int mt = 0; mt < 4; mt++) {
            const short* ap = vb + (size_t)s_idx[wv][mt * 16 + rw] * CV + q * 8;
            f32x4 a4 = {0.f, 0.f, 0.f, 0.f};
#pragma unroll
            for (int kc = 0; kc < CV; kc += 32) {
                bf16x8 av = *(const bf16x8*)(ap + kc);
                bf16x8 bv = *(const bf16x8*)(zp + kc);
                a4 = __builtin_amdgcn_mfma_f32_16x16x32_bf16(av, bv, a4, 0, 0, 0);
            }
            acc[mt] = a4;
        }
        if (rw == 0) {
#pragma unroll
            for (int mt = 0; mt < 4; mt++)
#pragma unroll
                for (int r = 0; r < 4; r++)
                    s_ps[wv][mt * 16 + q * 4 + r] = acc[mt][r];
        }
        __syncthreads();
        float p = expf((s_ps[wv][lane] + c0) * 0.03125f);
        float rs = p;
        for (int o = 32; o > 0; o >>= 1) rs += __shfl_xor(rs, o);
        s_ps[wv][lane] = p;
        if (lane == 0) {
            ws[RS_O + bt] = rs;
            atomicAdd(ws + DENOM_O + b, rs);
        }
        __syncthreads();
        // W accum from bf16 vision rows: lane covers cv = lane*4..+3
        float4 wa = {0.f, 0.f, 0.f, 0.f};
#pragma unroll 8
        for (int s = 0; s < S; s++) {
            float pv = s_ps[wv][s];
            s16x4 r4 = *(const s16x4*)(vb + (size_t)s_idx[wv][s] * CV + lane * 4);
            wa.x += pv * bf2f(r4.x); wa.y += pv * bf2f(r4.y);
            wa.z += pv * bf2f(r4.z); wa.w += pv * bf2f(r4.w);
        }
        s16x4 o;
        o.x = f2bf(wa.x); o.y = f2bf(wa.y); o.z = f2bf(wa.z); o.w = f2bf(wa.w);
        ((s16x4*)((short*)(ws + WB_O) + (size_t)bt * CV))[lane] = o;
    }
    gbar(bar, gen);

    // ================= phase E: out = x + (Wb @ WvpT^T + rs*bv)/denom ==========
    {
        int m0 = (gw >> 5) * 32, n0 = (gw & 31) * 32;
        const short* A = (const short*)(ws + WB_O) + (size_t)m0 * CV;
        const short* Bt = (const short*)(ws + WVPT_O) + (size_t)n0 * CV;
        f32x4 acc[2][2] = {};
        wave_mma<CV, CV, CV>(A, Bt, acc);
        int col = lane & 15, q = lane >> 4;
#pragma unroll
        for (int i = 0; i < 2; i++)
#pragma unroll
            for (int r = 0; r < 4; r++) {
                int row = m0 + i * 16 + q * 4 + r;
                float rs = ws[RS_O + row];
                float inv = 1.0f / ws[DENOM_O + (row >> 8)];
#pragma unroll
                for (int j = 0; j < 2; j++) {
                    int cc = n0 + j * 16 + col;
                    out[(size_t)row * DIM + cc] =
                        x[(size_t)row * DIM + cc] +
                        (acc[i][j][r] + rs * ws[BV_O + cc]) * inv;
                }
            }
    }
}

extern "C" void kernel_launch(void* const* d_in, const int* in_sizes, int n_in,
                              void* d_out, int out_size, void* d_ws, size_t ws_size,
                              hipStream_t stream) {
    (void)in_sizes; (void)n_in; (void)out_size; (void)ws_size;
    const float* x      = (const float*)d_in[0];
    const float* vision = (const float*)d_in[1];
    const void*  mask   = d_in[2];
    const float* Wu     = (const float*)d_in[3];
    const float* bu     = (const float*)d_in[4];
    const float* Wk     = (const float*)d_in[5];
    const float* Wv     = (const float*)d_in[6];
    float* out = (float*)d_out;
    float* ws  = (float*)d_ws;
    int*   wsi = (int*)d_ws;

    // zero bk/bv/denom/barrier state
    hipMemsetAsync((char*)d_ws + (size_t)BK_O * 4, 0,
                   (size_t)(WS_TOTAL - BK_O) * 4, stream);

    mega<<<NBLK, 256, 0, stream>>>(x, vision, mask, Wu, bu, Wk, Wv, ws, wsi, out);
}

// Round 8
// 299.535 us; speedup vs baseline: 1.0309x; 1.0309x over previous
//
#include <hip/hip_runtime.h>
#include <stdint.h>

#define B 4
#define T 256
#define V 1024
#define S 64
#define DIM 1024
#define CV 256
#define NBLK 512

typedef __attribute__((ext_vector_type(8))) short bf16x8;
typedef __attribute__((ext_vector_type(4))) short s16x4;
typedef __attribute__((ext_vector_type(4))) float f32x4;

// ---- workspace layout (4-byte word offsets; bf16 arrays counted in words) ----
enum : int {
    WKT_O   = 0,                  // [262144 w] WkT bf16 [DIM][DIM] (d-major)
    WVT_O   = WKT_O + 262144,     // [262144 w] WvT bf16 [DIM][DIM]
    WUB_O   = WVT_O + 262144,     // [131072 w] Wu bf16 [CV][DIM]
    WKPB_O  = WUB_O + 131072,     // [131072 w] Wkp bf16 [CV][DIM]   (B^T for z)
    WVPT_O  = WKPB_O + 131072,    // [131072 w] WvpT bf16 [DIM][CV]  (B^T for out)
    XB_O    = WVPT_O + 131072,    // [262144 w] x bf16 [B*T][DIM]
    ZB_O    = XB_O + 262144,      // [131072 w] Z bf16 [B*T][CV]
    VB_O    = ZB_O + 131072,      // [524288 w] vision bf16 [B][V][CV]
    WB_O    = VB_O + 524288,      // [131072 w] W bf16 [B*T][CV]
    C0_O    = WB_O + 131072,      // [B*T] f32 bk.x
    RS_O    = C0_O + B*T,         // [B*T] f32 row sums
    PIDX_O  = RS_O + B*T,         // [B*T*S] int selected v
    BK_O    = PIDX_O + B*T*S,     // [DIM] f32 bu@Wk  (zeroed, atomic target)
    BV_O    = BK_O + DIM,         // [DIM] f32 bu@Wv  (zeroed, atomic target)
    DENOM_O = BV_O + DIM,         // [B]   f32        (zeroed, atomic target)
    BAR0_O  = DENOM_O + B,        // [4] per-phase barrier counters (zeroed)
    WS_TOTAL= BAR0_O + 4
};

__device__ __forceinline__ short f2bf(float f) {
    union { float f; unsigned u; } x; x.f = f;
    unsigned r = (x.u + 0x7FFF + ((x.u >> 16) & 1)) >> 16;
    return (short)r;
}
__device__ __forceinline__ float bf2f(short s) {
    union { unsigned u; float f; } x;
    x.u = ((unsigned)(unsigned short)s) << 16;
    return x.f;
}
__device__ __forceinline__ s16x4 cvt4(float4 f) {
    s16x4 o;
    o.x = f2bf(f.x); o.y = f2bf(f.y); o.z = f2bf(f.z); o.w = f2bf(f.w);
    return o;
}

// ---- grid barrier: RELEASE arrive, RELAXED poll (no per-poll invalidate),
// ---- single ACQUIRE on exit. Dedicated counter per phase (no reset). ----
__device__ __forceinline__ void gbar(int* __restrict__ ctr) {
    __syncthreads();
    if (threadIdx.x == 0) {
        __hip_atomic_fetch_add(ctr, 1, __ATOMIC_RELEASE, __HIP_MEMORY_SCOPE_AGENT);
        while (__hip_atomic_load(ctr, __ATOMIC_RELAXED,
                                 __HIP_MEMORY_SCOPE_AGENT) < NBLK)
            __builtin_amdgcn_s_sleep(16);
        (void)__hip_atomic_load(ctr, __ATOMIC_ACQUIRE, __HIP_MEMORY_SCOPE_AGENT);
    }
    __syncthreads();
}

// ---- per-wave 16x16 MFMA tile: A[m][k] row-major, Bt[n][k] row-major ----
template<int K, int LDA, int LDB>
__device__ __forceinline__ void wave_mma16(const short* __restrict__ A0,
                                           const short* __restrict__ B0,
                                           f32x4& acc) {
    int lane = threadIdx.x & 63;
    int rw = lane & 15, q = lane >> 4;
    const short* ap = A0 + rw * LDA + q * 8;
    const short* bp = B0 + rw * LDB + q * 8;
#pragma unroll 8
    for (int kc = 0; kc < K; kc += 32) {
        bf16x8 a = *(const bf16x8*)(ap + kc);
        bf16x8 b = *(const bf16x8*)(bp + kc);
        acc = __builtin_amdgcn_mfma_f32_16x16x32_bf16(a, b, acc, 0, 0, 0);
    }
}

__global__ __launch_bounds__(256, 2)
void mega(const float* __restrict__ x, const float* __restrict__ vision,
          const void* __restrict__ maskp, const float* __restrict__ Wu,
          const float* __restrict__ bu, const float* __restrict__ Wk,
          const float* __restrict__ Wv, float* __restrict__ ws,
          int* __restrict__ wsi, float* __restrict__ out) {
    __shared__ short tlds[64 * 65];
    __shared__ float tred[4 * 64];
    __shared__ int mc_cnt[16][17];
    __shared__ int sa_flag, sb_flag;
    __shared__ int s_idx[4][64];
    __shared__ float s_ps[4][64];

    int tid = threadIdx.x;
    int lane = tid & 63, wv = tid >> 6;
    int gw = blockIdx.x * 4 + wv;          // global wave id, 0..2047
    int* bar = wsi + BAR0_O;

    // ================= phase A: converts + transpose/bias + mask ===============
    {
        int gtid = blockIdx.x * 256 + tid;   // 0..131071
        // vision f32 -> bf16 (262144 float4)
        {
            const float4* src = (const float4*)vision;
            s16x4* dst = (s16x4*)((short*)(ws + VB_O));
#pragma unroll
            for (int it = 0; it < 2; it++) {
                int i = it * 131072 + gtid;
                dst[i] = cvt4(src[i]);
            }
        }
        // Wu (65536 float4)
        if (gtid < 65536) {
            const float4* src = (const float4*)Wu;
            s16x4* dst = (s16x4*)((short*)(ws + WUB_O));
            dst[gtid] = cvt4(src[gtid]);
        }
        // x (262144 float4)
        {
            const float4* src = (const float4*)x;
            s16x4* dst = (s16x4*)((short*)(ws + XB_O));
#pragma unroll
            for (int it = 0; it < 2; it++) {
                int i = it * 131072 + gtid;
                dst[i] = cvt4(src[i]);
            }
        }
        // Wk/Wv transpose-convert + fused bias partials: 1 tile per block
        {
            int tile = blockIdx.x;
            int which = tile >> 8, t2 = tile & 255;
            int e0 = (t2 >> 4) * 64, d0 = (t2 & 15) * 64;
            const float* src = which ? Wv : Wk;
            short* dst = (short*)(ws + (which ? WVT_O : WKT_O));
            int j = tid & 63, i0 = tid >> 6;
            float pb = 0.f;
#pragma unroll
            for (int p = 0; p < 16; p++) {
                int i = p * 4 + i0;
                float v = src[(size_t)(e0 + i) * DIM + d0 + j];
                tlds[j * 65 + i] = f2bf(v);
                pb += bu[e0 + i] * v;
            }
            tred[i0 * 64 + j] = pb;
            __syncthreads();
#pragma unroll
            for (int p = 0; p < 16; p++) {
                int dd = p * 4 + i0;
                dst[(size_t)(d0 + dd) * DIM + e0 + j] = tlds[dd * 65 + j];
            }
            if (i0 == 0) {
                float s = tred[j] + tred[64 + j] + tred[128 + j] + tred[192 + j];
                atomicAdd(ws + (which ? BV_O : BK_O) + d0 + j, s);
            }
            __syncthreads();
        }
        // mask compaction: blocks 0..63, single pass via 64-bit bitmask
        if (blockIdx.x < 64) {
            {   // block-local encoding detection over first 4 KB
                int a = 0, bfl = 0;
                const uchar4* m4 = (const uchar4*)maskp;
#pragma unroll
                for (int jj = 0; jj < 4; jj++) {
                    uchar4 u = m4[tid * 4 + jj];
                    if (u.y | u.z | u.w) a = 1;
                    if (u.x == 0x3f || u.y == 0x3f || u.z == 0x3f || u.w == 0x3f)
                        bfl = 1;
                }
                if (tid == 0) { sa_flag = 0; sb_flag = 0; }
                __syncthreads();
                if (a) sa_flag = 1;
                if (bfl) sb_flag = 1;
                __syncthreads();
            }
            bool byteMode = sa_flag && !sb_flag;
            int b = blockIdx.x >> 4, tg = blockIdx.x & 15;
            int tl = tid & 15, c = tid >> 4;
            int t = tg * 16 + tl;
            int v0 = c * 64;
            unsigned long long bits = 0ull;
            if (byteMode) {
                const uint8_t* m = (const uint8_t*)maskp + (size_t)(b * V + v0) * T + t;
#pragma unroll 8
                for (int j = 0; j < 64; j++)
                    if (m[(size_t)j * T] != 0) bits |= 1ull << j;
            } else {
                const int* m = (const int*)maskp + (size_t)(b * V + v0) * T + t;
#pragma unroll 8
                for (int j = 0; j < 64; j++)
                    if (m[(size_t)j * T] != 0) bits |= 1ull << j;
            }
            mc_cnt[tl][c] = __popcll(bits);
            __syncthreads();
            int off = 0, total = 0;
#pragma unroll
            for (int cc = 0; cc < 16; cc++) {
                int cn = mc_cnt[tl][cc];
                if (cc < c) off += cn;
                total += cn;
            }
            int base = PIDX_O + (b * T + t) * S;
            while (bits) {
                int j = __ffsll(bits) - 1;
                bits &= bits - 1;
                if (off < S) wsi[base + off] = v0 + j;
                off++;
            }
            if (c == 15)
                for (int j = (total < S ? total : S); j < S; j++) wsi[base + j] = 0;
        }
    }
    gbar(bar + 0);

    // ==== phase B: Wkp/WvpT prep GEMMs (2048 16x16 tiles, 1/wave) + c0 =========
    {
        int which = gw >> 10, r = gw & 1023;
        int m0 = (r >> 6) * 16, n0 = (r & 63) * 16;  // m: cv(256), n: d(1024)
        const short* A = (const short*)(ws + WUB_O) + (size_t)m0 * DIM;
        const short* Bt = (const short*)(ws + (which ? WVT_O : WKT_O)) +
                          (size_t)n0 * DIM;
        f32x4 acc = {0.f, 0.f, 0.f, 0.f};
        wave_mma16<DIM, DIM, DIM>(A, Bt, acc);
        int col = lane & 15, q = lane >> 4;
        if (which == 0) {
            short* o = (short*)(ws + WKPB_O);
#pragma unroll
            for (int rr = 0; rr < 4; rr++)
                o[(size_t)(m0 + q * 4 + rr) * DIM + n0 + col] = f2bf(acc[rr]);
        } else {
            short* o = (short*)(ws + WVPT_O);
#pragma unroll
            for (int rr = 0; rr < 4; rr++)
                o[(size_t)(n0 + col) * CV + m0 + q * 4 + rr] = f2bf(acc[rr]);
        }
        // c0[bt] = xb[bt].bk  (waves 0..1023, 1 bt each)
        if (gw < 1024) {
            int bt = gw;
            const short* xr = (const short*)(ws + XB_O) + (size_t)bt * DIM;
            float a = 0.f;
#pragma unroll
            for (int jj = 0; jj < 4; jj++) {
                s16x4 xv = *(const s16x4*)(xr + jj * 256 + lane * 4);
                float4 k4 = *(const float4*)(ws + BK_O + jj * 256 + lane * 4);
                a += bf2f(xv.x) * k4.x + bf2f(xv.y) * k4.y +
                     bf2f(xv.z) * k4.z + bf2f(xv.w) * k4.w;
            }
            for (int o = 32; o > 0; o >>= 1) a += __shfl_xor(a, o);
            if (lane == 0) ws[C0_O + bt] = a;
        }
    }
    gbar(bar + 1);

    // ============ phase C: Z bf16 = Xb @ Wkp^T (1024 16x16 tiles) ==============
    if (gw < 1024) {
        int m0 = (gw >> 4) * 16, n0 = (gw & 15) * 16;  // m: bt(1024), n: cv(256)
        const short* A = (const short*)(ws + XB_O) + (size_t)m0 * DIM;
        const short* Bt = (const short*)(ws + WKPB_O) + (size_t)n0 * DIM;
        f32x4 acc = {0.f, 0.f, 0.f, 0.f};
        wave_mma16<DIM, DIM, DIM>(A, Bt, acc);
        int col = lane & 15, q = lane >> 4;
        short* zb = (short*)(ws + ZB_O);
#pragma unroll
        for (int rr = 0; rr < 4; rr++)
            zb[(size_t)(m0 + q * 4 + rr) * CV + n0 + col] = f2bf(acc[rr]);
    }
    gbar(bar + 2);

    // ================= phase D: attention per bt (waves 0..1023) ===============
    if (gw < 1024) {
        int bt = gw, b = bt >> 8;
        s_idx[wv][lane] = wsi[PIDX_O + bt * S + lane];
        float c0 = ws[C0_O + bt];
        int rw = lane & 15, q = lane >> 4;
        const short* vb = (const short*)(ws + VB_O) + (size_t)b * V * CV;
        const short* zp = (const short*)(ws + ZB_O) + (size_t)bt * CV + q * 8;
        f32x4 acc[4] = {};
#pragma unroll
        for (int mt = 0; mt < 4; mt++) {
            const short* ap = vb + (size_t)s_idx[wv][mt * 16 + rw] * CV + q * 8;
            f32x4 a4 = {0.f, 0.f, 0.f, 0.f};
#pragma unroll
            for (int kc = 0; kc < CV; kc += 32) {
                bf16x8 av = *(const bf16x8*)(ap + kc);
                bf16x8 bv = *(const bf16x8*)(zp + kc);
                a4 = __builtin_amdgcn_mfma_f32_16x16x32_bf16(av, bv, a4, 0, 0, 0);
            }
            acc[mt] = a4;
        }
        if (rw == 0) {
#pragma unroll
            for (int mt = 0; mt < 4; mt++)
#pragma unroll
                for (int r = 0; r < 4; r++)
                    s_ps[wv][mt * 16 + q * 4 + r] = acc[mt][r];
        }
        // wave-local: s_idx/s_ps touched only by this wave; lgkm drained by compiler
        float p = expf((s_ps[wv][lane] + c0) * 0.03125f);
        float rs = p;
        for (int o = 32; o > 0; o >>= 1) rs += __shfl_xor(rs, o);
        s_ps[wv][lane] = p;
        if (lane == 0) {
            ws[RS_O + bt] = rs;
            atomicAdd(ws + DENOM_O + b, rs);
        }
        // W accum from bf16 vision rows: lane covers cv = lane*4..+3
        float4 wa = {0.f, 0.f, 0.f, 0.f};
#pragma unroll 8
        for (int s = 0; s < S; s++) {
            float pv = s_ps[wv][s];
            s16x4 r4 = *(const s16x4*)(vb + (size_t)s_idx[wv][s] * CV + lane * 4);
            wa.x += pv * bf2f(r4.x); wa.y += pv * bf2f(r4.y);
            wa.z += pv * bf2f(r4.z); wa.w += pv * bf2f(r4.w);
        }
        s16x4 o;
        o.x = f2bf(wa.x); o.y = f2bf(wa.y); o.z = f2bf(wa.z); o.w = f2bf(wa.w);
        ((s16x4*)((short*)(ws + WB_O) + (size_t)bt * CV))[lane] = o;
    }
    gbar(bar + 3);

    // ===== phase E: out = x + (Wb @ WvpT^T + rs*bv)/denom (4096 tiles, 2/wave) ==
    {
        int col = lane & 15, q = lane >> 4;
#pragma unroll
        for (int tt = 0; tt < 2; tt++) {
            int tile = gw * 2 + tt;
            int m0 = (tile >> 6) * 16, n0 = (tile & 63) * 16;  // m: bt, n: d
            const short* A = (const short*)(ws + WB_O) + (size_t)m0 * CV;
            const short* Bt = (const short*)(ws + WVPT_O) + (size_t)n0 * CV;
            f32x4 acc = {0.f, 0.f, 0.f, 0.f};
            wave_mma16<CV, CV, CV>(A, Bt, acc);
#pragma unroll
            for (int rr = 0; rr < 4; rr++) {
                int row = m0 + q * 4 + rr;
                float rs = ws[RS_O + row];
                float inv = 1.0f / ws[DENOM_O + (row >> 8)];
                int cc = n0 + col;
                out[(size_t)row * DIM + cc] =
                    x[(size_t)row * DIM + cc] +
                    (acc[rr] + rs * ws[BV_O + cc]) * inv;
            }
        }
    }
}

extern "C" void kernel_launch(void* const* d_in, const int* in_sizes, int n_in,
                              void* d_out, int out_size, void* d_ws, size_t ws_size,
                              hipStream_t stream) {
    (void)in_sizes; (void)n_in; (void)out_size; (void)ws_size;
    const float* x      = (const float*)d_in[0];
    const float* vision = (const float*)d_in[1];
    const void*  mask   = d_in[2];
    const float* Wu     = (const float*)d_in[3];
    const float* bu     = (const float*)d_in[4];
    const float* Wk     = (const float*)d_in[5];
    const float* Wv     = (const float*)d_in[6];
    float* out = (float*)d_out;
    float* ws  = (float*)d_ws;
    int*   wsi = (int*)d_ws;

    // zero bk/bv/denom + barrier counters
    hipMemsetAsync((char*)d_ws + (size_t)BK_O * 4, 0,
                   (size_t)(WS_TOTAL - BK_O) * 4, stream);

    mega<<<NBLK, 256, 0, stream>>>(x, vision, mask, Wu, bu, Wk, Wv, ws, wsi, out);
}

// Round 9
// 216.134 us; speedup vs baseline: 1.4288x; 1.3859x over previous
//
#include <hip/hip_runtime.h>
#include <stdint.h>

#define B 4
#define T 256
#define V 1024
#define S 64
#define DIM 1024
#define CV 256
#define NBLK 512

typedef __attribute__((ext_vector_type(8))) short bf16x8;
typedef __attribute__((ext_vector_type(4))) short s16x4;
typedef __attribute__((ext_vector_type(4))) float f32x4;

// ---- workspace layout (4-byte word offsets; bf16 arrays counted in words) ----
enum : int {
    WKT_O   = 0,                  // [262144 w] WkT bf16 [DIM][DIM] (d-major)
    WVT_O   = WKT_O + 262144,     // [262144 w] WvT bf16 [DIM][DIM]
    WUB_O   = WVT_O + 262144,     // [131072 w] Wu bf16 [CV][DIM]
    WKPB_O  = WUB_O + 131072,     // [131072 w] Wkp bf16 [CV][DIM]   (B^T for z)
    WVPT_O  = WKPB_O + 131072,    // [131072 w] WvpT bf16 [DIM][CV]  (B^T for out)
    XB_O    = WVPT_O + 131072,    // [262144 w] x bf16 [B*T][DIM]
    ZB_O    = XB_O + 262144,      // [131072 w] Z bf16 [B*T][CV]
    VB_O    = ZB_O + 131072,      // [524288 w] vision bf16 [B][V][CV]
    WB_O    = VB_O + 524288,      // [131072 w] W bf16 [B*T][CV]
    C0_O    = WB_O + 131072,      // [B*T] f32 bk.x
    RS_O    = C0_O + B*T,         // [B*T] f32 row sums
    PIDX_O  = RS_O + B*T,         // [B*T*S] int selected v
    BK_O    = PIDX_O + B*T*S,     // [DIM] f32 bu@Wk  (zeroed, atomic target)
    BV_O    = BK_O + DIM,         // [DIM] f32 bu@Wv  (zeroed, atomic target)
    DENOM_O = BV_O + DIM,         // [B]   f32        (zeroed, atomic target)
    ARR_O   = DENOM_O + B + 28,   // [16*32] striped arrival counters (zeroed, 128B apart)
    GO_O    = ARR_O + 16*32,      // [8*32]  striped go-flags         (zeroed)
    WS_TOTAL= GO_O + 8*32
};

__device__ __forceinline__ short f2bf(float f) {
    union { float f; unsigned u; } x; x.f = f;
    unsigned r = (x.u + 0x7FFF + ((x.u >> 16) & 1)) >> 16;
    return (short)r;
}
__device__ __forceinline__ float bf2f(short s) {
    union { unsigned u; float f; } x;
    x.u = ((unsigned)(unsigned short)s) << 16;
    return x.f;
}
__device__ __forceinline__ s16x4 cvt4(float4 f) {
    s16x4 o;
    o.x = f2bf(f.x); o.y = f2bf(f.y); o.z = f2bf(f.z); o.w = f2bf(f.w);
    return o;
}

// ---- grid barrier: striped arrivals + manager broadcast (hot-line convoy fix) ----
// Arrivals spread over 16 lines; only block 0 polls them; workers poll one of
// 8 go-lines at ~1 µs cadence. Phase is monotonic (no counter reset).
__device__ __forceinline__ void gbar(int* __restrict__ arr, int* __restrict__ go,
                                     int phase) {
    __syncthreads();
    if (threadIdx.x == 0) {
        __hip_atomic_fetch_add(&arr[(blockIdx.x & 15) * 32], 1,
                               __ATOMIC_RELEASE, __HIP_MEMORY_SCOPE_AGENT);
        if (blockIdx.x == 0) {
            for (;;) {
                int total = 0;
#pragma unroll
                for (int i = 0; i < 16; i++)
                    total += __hip_atomic_load(&arr[i * 32], __ATOMIC_RELAXED,
                                               __HIP_MEMORY_SCOPE_AGENT);
                if (total >= NBLK * phase) break;
                __builtin_amdgcn_s_sleep(8);
            }
            (void)__hip_atomic_load(&arr[0], __ATOMIC_ACQUIRE,
                                    __HIP_MEMORY_SCOPE_AGENT);
#pragma unroll
            for (int i = 0; i < 8; i++)
                __hip_atomic_store(&go[i * 32], phase, __ATOMIC_RELEASE,
                                   __HIP_MEMORY_SCOPE_AGENT);
        } else {
            int* myGo = &go[(blockIdx.x & 7) * 32];
            while (__hip_atomic_load(myGo, __ATOMIC_RELAXED,
                                     __HIP_MEMORY_SCOPE_AGENT) < phase)
                __builtin_amdgcn_s_sleep(32);
            (void)__hip_atomic_load(myGo, __ATOMIC_ACQUIRE,
                                    __HIP_MEMORY_SCOPE_AGENT);
        }
    }
    __syncthreads();
}

// ---- per-wave 16x16 MFMA tile: A[m][k] row-major, Bt[n][k] row-major ----
template<int K, int LDA, int LDB>
__device__ __forceinline__ void wave_mma16(const short* __restrict__ A0,
                                           const short* __restrict__ B0,
                                           f32x4& acc) {
    int lane = threadIdx.x & 63;
    int rw = lane & 15, q = lane >> 4;
    const short* ap = A0 + rw * LDA + q * 8;
    const short* bp = B0 + rw * LDB + q * 8;
#pragma unroll 8
    for (int kc = 0; kc < K; kc += 32) {
        bf16x8 a = *(const bf16x8*)(ap + kc);
        bf16x8 b = *(const bf16x8*)(bp + kc);
        acc = __builtin_amdgcn_mfma_f32_16x16x32_bf16(a, b, acc, 0, 0, 0);
    }
}

__global__ __launch_bounds__(256, 2)
void mega(const float* __restrict__ x, const float* __restrict__ vision,
          const void* __restrict__ maskp, const float* __restrict__ Wu,
          const float* __restrict__ bu, const float* __restrict__ Wk,
          const float* __restrict__ Wv, float* __restrict__ ws,
          int* __restrict__ wsi, float* __restrict__ out) {
    __shared__ short tlds[64 * 65];
    __shared__ float tred[4 * 64];
    __shared__ int mc_cnt[16][17];
    __shared__ int sa_flag, sb_flag;
    __shared__ int s_idx[4][64];
    __shared__ float s_ps[4][64];

    int tid = threadIdx.x;
    int lane = tid & 63, wv = tid >> 6;
    int gw = blockIdx.x * 4 + wv;          // global wave id, 0..2047
    int* arr = wsi + ARR_O;
    int* go  = wsi + GO_O;

    // ================= phase A: converts + transpose/bias + mask ===============
    {
        int gtid = blockIdx.x * 256 + tid;   // 0..131071
        // vision f32 -> bf16 (262144 float4)
        {
            const float4* src = (const float4*)vision;
            s16x4* dst = (s16x4*)((short*)(ws + VB_O));
#pragma unroll
            for (int it = 0; it < 2; it++) {
                int i = it * 131072 + gtid;
                dst[i] = cvt4(src[i]);
            }
        }
        // Wu (65536 float4)
        if (gtid < 65536) {
            const float4* src = (const float4*)Wu;
            s16x4* dst = (s16x4*)((short*)(ws + WUB_O));
            dst[gtid] = cvt4(src[gtid]);
        }
        // x (262144 float4)
        {
            const float4* src = (const float4*)x;
            s16x4* dst = (s16x4*)((short*)(ws + XB_O));
#pragma unroll
            for (int it = 0; it < 2; it++) {
                int i = it * 131072 + gtid;
                dst[i] = cvt4(src[i]);
            }
        }
        // Wk/Wv transpose-convert + fused bias partials: 1 tile per block
        {
            int tile = blockIdx.x;
            int which = tile >> 8, t2 = tile & 255;
            int e0 = (t2 >> 4) * 64, d0 = (t2 & 15) * 64;
            const float* src = which ? Wv : Wk;
            short* dst = (short*)(ws + (which ? WVT_O : WKT_O));
            int j = tid & 63, i0 = tid >> 6;
            float pb = 0.f;
#pragma unroll
            for (int p = 0; p < 16; p++) {
                int i = p * 4 + i0;
                float v = src[(size_t)(e0 + i) * DIM + d0 + j];
                tlds[j * 65 + i] = f2bf(v);
                pb += bu[e0 + i] * v;
            }
            tred[i0 * 64 + j] = pb;
            __syncthreads();
#pragma unroll
            for (int p = 0; p < 16; p++) {
                int dd = p * 4 + i0;
                dst[(size_t)(d0 + dd) * DIM + e0 + j] = tlds[dd * 65 + j];
            }
            if (i0 == 0) {
                float s = tred[j] + tred[64 + j] + tred[128 + j] + tred[192 + j];
                atomicAdd(ws + (which ? BV_O : BK_O) + d0 + j, s);
            }
            __syncthreads();
        }
        // mask compaction: blocks 0..63, single pass via 64-bit bitmask
        if (blockIdx.x < 64) {
            {   // block-local encoding detection over first 4 KB
                int a = 0, bfl = 0;
                const uchar4* m4 = (const uchar4*)maskp;
#pragma unroll
                for (int jj = 0; jj < 4; jj++) {
                    uchar4 u = m4[tid * 4 + jj];
                    if (u.y | u.z | u.w) a = 1;
                    if (u.x == 0x3f || u.y == 0x3f || u.z == 0x3f || u.w == 0x3f)
                        bfl = 1;
                }
                if (tid == 0) { sa_flag = 0; sb_flag = 0; }
                __syncthreads();
                if (a) sa_flag = 1;
                if (bfl) sb_flag = 1;
                __syncthreads();
            }
            bool byteMode = sa_flag && !sb_flag;
            int b = blockIdx.x >> 4, tg = blockIdx.x & 15;
            int tl = tid & 15, c = tid >> 4;
            int t = tg * 16 + tl;
            int v0 = c * 64;
            unsigned long long bits = 0ull;
            if (byteMode) {
                const uint8_t* m = (const uint8_t*)maskp + (size_t)(b * V + v0) * T + t;
#pragma unroll 8
                for (int j = 0; j < 64; j++)
                    if (m[(size_t)j * T] != 0) bits |= 1ull << j;
            } else {
                const int* m = (const int*)maskp + (size_t)(b * V + v0) * T + t;
#pragma unroll 8
                for (int j = 0; j < 64; j++)
                    if (m[(size_t)j * T] != 0) bits |= 1ull << j;
            }
            mc_cnt[tl][c] = __popcll(bits);
            __syncthreads();
            int off = 0, total = 0;
#pragma unroll
            for (int cc = 0; cc < 16; cc++) {
                int cn = mc_cnt[tl][cc];
                if (cc < c) off += cn;
                total += cn;
            }
            int base = PIDX_O + (b * T + t) * S;
            while (bits) {
                int j = __ffsll(bits) - 1;
                bits &= bits - 1;
                if (off < S) wsi[base + off] = v0 + j;
                off++;
            }
            if (c == 15)
                for (int j = (total < S ? total : S); j < S; j++) wsi[base + j] = 0;
        }
    }
    gbar(arr, go, 1);

    // ==== phase B: Wkp/WvpT prep GEMMs (2048 16x16 tiles, 1/wave) + c0 =========
    {
        int which = gw >> 10, r = gw & 1023;
        int m0 = (r >> 6) * 16, n0 = (r & 63) * 16;  // m: cv(256), n: d(1024)
        const short* A = (const short*)(ws + WUB_O) + (size_t)m0 * DIM;
        const short* Bt = (const short*)(ws + (which ? WVT_O : WKT_O)) +
                          (size_t)n0 * DIM;
        f32x4 acc = {0.f, 0.f, 0.f, 0.f};
        wave_mma16<DIM, DIM, DIM>(A, Bt, acc);
        int col = lane & 15, q = lane >> 4;
        if (which == 0) {
            short* o = (short*)(ws + WKPB_O);
#pragma unroll
            for (int rr = 0; rr < 4; rr++)
                o[(size_t)(m0 + q * 4 + rr) * DIM + n0 + col] = f2bf(acc[rr]);
        } else {
            short* o = (short*)(ws + WVPT_O);
#pragma unroll
            for (int rr = 0; rr < 4; rr++)
                o[(size_t)(n0 + col) * CV + m0 + q * 4 + rr] = f2bf(acc[rr]);
        }
        // c0[bt] = xb[bt].bk  (waves 0..1023, 1 bt each)
        if (gw < 1024) {
            int bt = gw;
            const short* xr = (const short*)(ws + XB_O) + (size_t)bt * DIM;
            float a = 0.f;
#pragma unroll
            for (int jj = 0; jj < 4; jj++) {
                s16x4 xv = *(const s16x4*)(xr + jj * 256 + lane * 4);
                float4 k4 = *(const float4*)(ws + BK_O + jj * 256 + lane * 4);
                a += bf2f(xv.x) * k4.x + bf2f(xv.y) * k4.y +
                     bf2f(xv.z) * k4.z + bf2f(xv.w) * k4.w;
            }
            for (int o = 32; o > 0; o >>= 1) a += __shfl_xor(a, o);
            if (lane == 0) ws[C0_O + bt] = a;
        }
    }
    gbar(arr, go, 2);

    // ============ phase C: Z bf16 = Xb @ Wkp^T (1024 16x16 tiles) ==============
    if (gw < 1024) {
        int m0 = (gw >> 4) * 16, n0 = (gw & 15) * 16;  // m: bt(1024), n: cv(256)
        const short* A = (const short*)(ws + XB_O) + (size_t)m0 * DIM;
        const short* Bt = (const short*)(ws + WKPB_O) + (size_t)n0 * DIM;
        f32x4 acc = {0.f, 0.f, 0.f, 0.f};
        wave_mma16<DIM, DIM, DIM>(A, Bt, acc);
        int col = lane & 15, q = lane >> 4;
        short* zb = (short*)(ws + ZB_O);
#pragma unroll
        for (int rr = 0; rr < 4; rr++)
            zb[(size_t)(m0 + q * 4 + rr) * CV + n0 + col] = f2bf(acc[rr]);
    }
    gbar(arr, go, 3);

    // ================= phase D: attention per bt (waves 0..1023) ===============
    if (gw < 1024) {
        int bt = gw, b = bt >> 8;
        s_idx[wv][lane] = wsi[PIDX_O + bt * S + lane];
        float c0 = ws[C0_O + bt];
        int rw = lane & 15, q = lane >> 4;
        const short* vb = (const short*)(ws + VB_O) + (size_t)b * V * CV;
        const short* zp = (const short*)(ws + ZB_O) + (size_t)bt * CV + q * 8;
        f32x4 acc[4] = {};
#pragma unroll
        for (int mt = 0; mt < 4; mt++) {
            const short* ap = vb + (size_t)s_idx[wv][mt * 16 + rw] * CV + q * 8;
            f32x4 a4 = {0.f, 0.f, 0.f, 0.f};
#pragma unroll
            for (int kc = 0; kc < CV; kc += 32) {
                bf16x8 av = *(const bf16x8*)(ap + kc);
                bf16x8 bv = *(const bf16x8*)(zp + kc);
                a4 = __builtin_amdgcn_mfma_f32_16x16x32_bf16(av, bv, a4, 0, 0, 0);
            }
            acc[mt] = a4;
        }
        if (rw == 0) {
#pragma unroll
            for (int mt = 0; mt < 4; mt++)
#pragma unroll
                for (int r = 0; r < 4; r++)
                    s_ps[wv][mt * 16 + q * 4 + r] = acc[mt][r];
        }
        float p = expf((s_ps[wv][lane] + c0) * 0.03125f);
        float rs = p;
        for (int o = 32; o > 0; o >>= 1) rs += __shfl_xor(rs, o);
        s_ps[wv][lane] = p;
        if (lane == 0) {
            ws[RS_O + bt] = rs;
            atomicAdd(ws + DENOM_O + b, rs);
        }
        // W accum from bf16 vision rows: lane covers cv = lane*4..+3
        float4 wa = {0.f, 0.f, 0.f, 0.f};
#pragma unroll 8
        for (int s = 0; s < S; s++) {
            float pv = s_ps[wv][s];
            s16x4 r4 = *(const s16x4*)(vb + (size_t)s_idx[wv][s] * CV + lane * 4);
            wa.x += pv * bf2f(r4.x); wa.y += pv * bf2f(r4.y);
            wa.z += pv * bf2f(r4.z); wa.w += pv * bf2f(r4.w);
        }
        s16x4 o;
        o.x = f2bf(wa.x); o.y = f2bf(wa.y); o.z = f2bf(wa.z); o.w = f2bf(wa.w);
        ((s16x4*)((short*)(ws + WB_O) + (size_t)bt * CV))[lane] = o;
    }
    gbar(arr, go, 4);

    // ===== phase E: out = x + (Wb @ WvpT^T + rs*bv)/denom (4096 tiles, 2/wave) ==
    {
        int col = lane & 15, q = lane >> 4;
#pragma unroll
        for (int tt = 0; tt < 2; tt++) {
            int tile = gw * 2 + tt;
            int m0 = (tile >> 6) * 16, n0 = (tile & 63) * 16;  // m: bt, n: d
            const short* A = (const short*)(ws + WB_O) + (size_t)m0 * CV;
            const short* Bt = (const short*)(ws + WVPT_O) + (size_t)n0 * CV;
            f32x4 acc = {0.f, 0.f, 0.f, 0.f};
            wave_mma16<CV, CV, CV>(A, Bt, acc);
#pragma unroll
            for (int rr = 0; rr < 4; rr++) {
                int row = m0 + q * 4 + rr;
                float rs = ws[RS_O + row];
                float inv = 1.0f / ws[DENOM_O + (row >> 8)];
                int cc = n0 + col;
                out[(size_t)row * DIM + cc] =
                    x[(size_t)row * DIM + cc] +
                    (acc[rr] + rs * ws[BV_O + cc]) * inv;
            }
        }
    }
}

extern "C" void kernel_launch(void* const* d_in, const int* in_sizes, int n_in,
                              void* d_out, int out_size, void* d_ws, size_t ws_size,
                              hipStream_t stream) {
    (void)in_sizes; (void)n_in; (void)out_size; (void)ws_size;
    const float* x      = (const float*)d_in[0];
    const float* vision = (const float*)d_in[1];
    const void*  mask   = d_in[2];
    const float* Wu     = (const float*)d_in[3];
    const float* bu     = (const float*)d_in[4];
    const float* Wk     = (const float*)d_in[5];
    const float* Wv     = (const float*)d_in[6];
    float* out = (float*)d_out;
    float* ws  = (float*)d_ws;
    int*   wsi = (int*)d_ws;

    // zero bk/bv/denom + barrier stripes
    hipMemsetAsync((char*)d_ws + (size_t)BK_O * 4, 0,
                   (size_t)(WS_TOTAL - BK_O) * 4, stream);

    mega<<<NBLK, 256, 0, stream>>>(x, vision, mask, Wu, bu, Wk, Wv, ws, wsi, out);
}

// Round 10
// 140.671 us; speedup vs baseline: 2.1952x; 1.5365x over previous
//
#include <hip/hip_runtime.h>
#include <stdint.h>

#define B 4
#define T 256
#define V 1024
#define S 64
#define DIM 1024
#define CV 256

typedef __attribute__((ext_vector_type(8))) short bf16x8;
typedef __attribute__((ext_vector_type(4))) short s16x4;
typedef __attribute__((ext_vector_type(4))) float f32x4;

// ---- workspace layout (4-byte word offsets; bf16 arrays counted in words) ----
// No zero-init required anywhere: every cell is unconditionally written each
// launch before it is read (harness poisons ws with 0xAA).
enum : int {
    WKT_O   = 0,                  // [262144 w] WkT bf16 [DIM][DIM] (d-major)
    WVT_O   = WKT_O + 262144,     // [262144 w] WvT bf16 [DIM][DIM]
    WUB_O   = WVT_O + 262144,     // [131072 w] Wu bf16 [CV][DIM]
    WKPB_O  = WUB_O + 131072,     // [131072 w] Wkp bf16 [CV][DIM]   (B^T for z)
    WVPT_O  = WKPB_O + 131072,    // [131072 w] WvpT bf16 [DIM][CV]  (B^T for out)
    XB_O    = WVPT_O + 131072,    // [262144 w] x bf16 [B*T][DIM]
    ZB_O    = XB_O + 262144,      // [131072 w] Z bf16 [B*T][CV]
    VB_O    = ZB_O + 131072,      // [524288 w] vision bf16 [B][V][CV]
    WB_O    = VB_O + 524288,      // [131072 w] W bf16 [B*T][CV]
    RS_O    = WB_O + 131072,      // [B*T] f32 row sums
    PIDX_O  = RS_O + B*T,         // [B*T*S] int selected v
    BK_O    = PIDX_O + B*T*S,     // [DIM] f32 bu@Wk  (written by g_prep blk 128)
    BV_O    = BK_O + DIM,         // [DIM] f32 bu@Wv  (written by g_prep blk 129)
    BP_O    = BV_O + DIM,         // [2][16][1024] f32 bias partials (stage1)
    WS_TOTAL= BP_O + 2*16*1024
};

__device__ __forceinline__ short f2bf(float f) {
    union { float f; unsigned u; } x; x.f = f;
    unsigned r = (x.u + 0x7FFF + ((x.u >> 16) & 1)) >> 16;
    return (short)r;
}
__device__ __forceinline__ float bf2f(short s) {
    union { unsigned u; float f; } x;
    x.u = ((unsigned)(unsigned short)s) << 16;
    return x.f;
}
__device__ __forceinline__ s16x4 cvt4(float4 f) {
    s16x4 o;
    o.x = f2bf(f.x); o.y = f2bf(f.y); o.z = f2bf(f.z); o.w = f2bf(f.w);
    return o;
}

// ================= stage 1: all input conversion + mask compaction =============
// blocks [0,1024)    : vision f32 -> bf16
// blocks [1024,1280) : Wu f32 -> bf16
// blocks [1280,2304) : x f32 -> bf16
// blocks [2304,2816) : Wk/Wv transpose-convert -> bf16 [d][e] + bias partials
// blocks [2816,2880) : mask compaction (self-detecting encoding)
__global__ void stage1(const float* __restrict__ vision, const float* __restrict__ Wu,
                       const float* __restrict__ x, const float* __restrict__ Wk,
                       const float* __restrict__ Wv, const float* __restrict__ bu,
                       const void* __restrict__ maskp,
                       float* __restrict__ ws, int* __restrict__ wsi) {
    __shared__ short tlds[64 * 65];
    __shared__ float tred[4 * 64];
    __shared__ int mc_cnt[16][17];
    __shared__ int sa_flag, sb_flag;
    int blk = blockIdx.x;
    int tid = threadIdx.x;

    if (blk < 2304) {  // ---- straight f32 -> bf16 converts ----
        const float* src; short* dst; int idx;
        if (blk < 1024)      { src = vision; dst = (short*)(ws + VB_O);  idx = blk; }
        else if (blk < 1280) { src = Wu;     dst = (short*)(ws + WUB_O); idx = blk - 1024; }
        else                 { src = x;      dst = (short*)(ws + XB_O);  idx = blk - 1280; }
        int i = (idx * 256 + tid);
        ((s16x4*)dst)[i] = cvt4(((const float4*)src)[i]);
        return;
    }
    if (blk < 2816) {  // ---- transpose-convert Wk/Wv + bias partials (no atomics) ----
        int tile = blk - 2304;
        int which = tile >> 8, t2 = tile & 255;
        int e0 = (t2 >> 4) * 64, d0 = (t2 & 15) * 64;
        const float* src = which ? Wv : Wk;
        short* dst = (short*)(ws + (which ? WVT_O : WKT_O));
        int j = tid & 63, i0 = tid >> 6;
        float pb = 0.f;
#pragma unroll
        for (int p = 0; p < 16; p++) {
            int i = p * 4 + i0;
            float v = src[(size_t)(e0 + i) * DIM + d0 + j];
            tlds[j * 65 + i] = f2bf(v);
            pb += bu[e0 + i] * v;
        }
        tred[i0 * 64 + j] = pb;
        __syncthreads();
#pragma unroll
        for (int p = 0; p < 16; p++) {
            int dd = p * 4 + i0;
            dst[(size_t)(d0 + dd) * DIM + e0 + j] = tlds[dd * 65 + j];
        }
        if (i0 == 0) {
            float s = tred[j] + tred[64 + j] + tred[128 + j] + tred[192 + j];
            ws[BP_O + (which * 16 + (e0 >> 6)) * 1024 + d0 + j] = s;
        }
        return;
    }
    // ---- mask compaction with block-local encoding detection ----
    {
        int a = 0, bfl = 0;
        const uchar4* m4 = (const uchar4*)maskp;
#pragma unroll
        for (int jj = 0; jj < 4; jj++) {
            uchar4 u = m4[tid * 4 + jj];
            if (u.y | u.z | u.w) a = 1;
            if (u.x == 0x3f || u.y == 0x3f || u.z == 0x3f || u.w == 0x3f) bfl = 1;
        }
        if (tid == 0) { sa_flag = 0; sb_flag = 0; }
        __syncthreads();
        if (a) sa_flag = 1;
        if (bfl) sb_flag = 1;
        __syncthreads();
    }
    bool byteMode = sa_flag && !sb_flag;
    int mb = blk - 2816;
    int b = mb >> 4, tg = mb & 15;
    int tl = tid & 15, c = tid >> 4;
    int t = tg * 16 + tl;
    int v0 = c * 64;
    unsigned long long bits = 0ull;
    if (byteMode) {
        const uint8_t* m = (const uint8_t*)maskp + (size_t)(b * V + v0) * T + t;
#pragma unroll 8
        for (int j = 0; j < 64; j++)
            if (m[(size_t)j * T] != 0) bits |= 1ull << j;
    } else {
        const int* m = (const int*)maskp + (size_t)(b * V + v0) * T + t;
#pragma unroll 8
        for (int j = 0; j < 64; j++)
            if (m[(size_t)j * T] != 0) bits |= 1ull << j;
    }
    mc_cnt[tl][c] = __popcll(bits);
    __syncthreads();
    int off = 0, total = 0;
#pragma unroll
    for (int cc = 0; cc < 16; cc++) {
        int cn = mc_cnt[tl][cc];
        if (cc < c) off += cn;
        total += cn;
    }
    int base = PIDX_O + (b * T + t) * S;
    while (bits) {
        int j = __ffsll(bits) - 1;
        bits &= bits - 1;
        if (off < S) wsi[base + off] = v0 + j;
        off++;
    }
    if (c == 15)
        for (int j = (total < S ? total : S); j < S; j++) wsi[base + j] = 0;
}

// ---- per-wave 32x32 MFMA tile: A[m][k] row-major, Bt[n][k] row-major ----
template<int K, int LDA, int LDB>
__device__ __forceinline__ void wave_mma(const short* __restrict__ A0,
                                         const short* __restrict__ B0,
                                         f32x4 acc[2][2]) {
    int lane = threadIdx.x & 63;
    int rw = lane & 15, q = lane >> 4;
    const short* ap0 = A0 + rw * LDA + q * 8;
    const short* ap1 = ap0 + 16 * LDA;
    const short* bp0 = B0 + rw * LDB + q * 8;
    const short* bp1 = bp0 + 16 * LDB;
#pragma unroll 4
    for (int kc = 0; kc < K; kc += 32) {
        bf16x8 a0 = *(const bf16x8*)(ap0 + kc);
        bf16x8 a1 = *(const bf16x8*)(ap1 + kc);
        bf16x8 b0 = *(const bf16x8*)(bp0 + kc);
        bf16x8 b1 = *(const bf16x8*)(bp1 + kc);
        acc[0][0] = __builtin_amdgcn_mfma_f32_16x16x32_bf16(a0, b0, acc[0][0], 0, 0, 0);
        acc[0][1] = __builtin_amdgcn_mfma_f32_16x16x32_bf16(a0, b1, acc[0][1], 0, 0, 0);
        acc[1][0] = __builtin_amdgcn_mfma_f32_16x16x32_bf16(a1, b0, acc[1][0], 0, 0, 0);
        acc[1][1] = __builtin_amdgcn_mfma_f32_16x16x32_bf16(a1, b1, acc[1][1], 0, 0, 0);
    }
}

// ---- g_prep: 130 blocks x 256 thr. Blocks 0..127: 512 32x32 wave-tiles of
// ---- Wkp = Wu@Wk (bf16 [cv][d]) / WvpT = (Wu@Wv)^T (bf16 [d][cv]).
// ---- Blocks 128/129: reduce bias partials -> bk / bv. ----
__global__ void g_prep_mfma(float* __restrict__ ws) {
    if (blockIdx.x >= 128) {
        int which = blockIdx.x - 128;
#pragma unroll
        for (int cch = 0; cch < 4; cch++) {
            int d = cch * 256 + threadIdx.x;
            float s = 0.f;
#pragma unroll
            for (int g = 0; g < 16; g++)
                s += ws[BP_O + (which * 16 + g) * 1024 + d];
            ws[(which ? BV_O : BK_O) + d] = s;
        }
        return;
    }
    int w = blockIdx.x * 4 + (threadIdx.x >> 6);     // 512 wave-tiles
    int which = w >> 8, rem = w & 255;
    int m0 = (rem >> 5) * 32, n0 = (rem & 31) * 32;  // m: cv(256), n: d(1024)
    const short* A = (const short*)(ws + WUB_O) + (size_t)m0 * DIM;
    const short* Bt = (const short*)(ws + (which ? WVT_O : WKT_O)) + (size_t)n0 * DIM;
    f32x4 acc[2][2] = {};
    wave_mma<DIM, DIM, DIM>(A, Bt, acc);
    int lane = threadIdx.x & 63, col = lane & 15, q = lane >> 4;
    if (which == 0) {
        short* o = (short*)(ws + WKPB_O);
#pragma unroll
        for (int i = 0; i < 2; i++)
#pragma unroll
            for (int j = 0; j < 2; j++)
#pragma unroll
                for (int r = 0; r < 4; r++)
                    o[(size_t)(m0 + i * 16 + q * 4 + r) * DIM + n0 + j * 16 + col] =
                        f2bf(acc[i][j][r]);
    } else {
        short* o = (short*)(ws + WVPT_O);
#pragma unroll
        for (int i = 0; i < 2; i++)
#pragma unroll
            for (int j = 0; j < 2; j++) {
                s16x4 v;
                v.x = f2bf(acc[i][j][0]); v.y = f2bf(acc[i][j][1]);
                v.z = f2bf(acc[i][j][2]); v.w = f2bf(acc[i][j][3]);
                *(s16x4*)&o[(size_t)(n0 + j * 16 + col) * CV + m0 + i * 16 + q * 4] = v;
            }
    }
}

// ---- g_z: Z bf16 [bt][cv] = Xb @ Wkp^T; 64 blocks x 4 waves (256 tiles) ----
__global__ void g_z_mfma(float* __restrict__ ws) {
    int w = blockIdx.x * 4 + (threadIdx.x >> 6);
    int m0 = (w >> 3) * 32, n0 = (w & 7) * 32;     // m: bt(1024), n: cv(256)
    const short* A = (const short*)(ws + XB_O) + (size_t)m0 * DIM;
    const short* Bt = (const short*)(ws + WKPB_O) + (size_t)n0 * DIM;
    f32x4 acc[2][2] = {};
    wave_mma<DIM, DIM, DIM>(A, Bt, acc);
    int lane = threadIdx.x & 63, col = lane & 15, q = lane >> 4;
    short* zb = (short*)(ws + ZB_O);
#pragma unroll
    for (int i = 0; i < 2; i++)
#pragma unroll
        for (int j = 0; j < 2; j++)
#pragma unroll
            for (int r = 0; r < 4; r++)
                zb[(size_t)(m0 + i * 16 + q * 4 + r) * CV + n0 + j * 16 + col] =
                    f2bf(acc[i][j][r]);
}

// ---- g_attn: per (b,t) wave: c0 = x.bk; scores via gathered MFMA; exp;
// ---- RS store (no atomic); W bf16 = sum p*vis_row. 256 blocks x 4 waves ----
__global__ void g_attn(const float* __restrict__ x, float* __restrict__ ws,
                       int* __restrict__ wsi) {
    __shared__ int s_idx[4][64];
    __shared__ float s_ps[4][64];
    int tid = threadIdx.x;
    int lane = tid & 63, wv = tid >> 6;
    int bt = blockIdx.x * 4 + wv, b = bt >> 8;
    s_idx[wv][lane] = wsi[PIDX_O + bt * S + lane];    // S == 64
    // c0 = x[bt] . bk  (f32, wave butterfly)
    float c0p = 0.f;
    const float4* xr = (const float4*)(x + (size_t)bt * DIM);
    const float4* bkr = (const float4*)(ws + BK_O);
#pragma unroll
    for (int j = 0; j < 4; j++) {
        float4 a = xr[lane + 64 * j], k4 = bkr[lane + 64 * j];
        c0p += a.x * k4.x + a.y * k4.y + a.z * k4.z + a.w * k4.w;
    }
    for (int o = 32; o > 0; o >>= 1) c0p += __shfl_xor(c0p, o);
    float c0 = c0p;
    // scores: A = 16 gathered bf16 vision rows, B = z broadcast into 16 cols
    int rw = lane & 15, q = lane >> 4;
    const short* vb = (const short*)(ws + VB_O) + (size_t)b * V * CV;
    const short* zp = (const short*)(ws + ZB_O) + (size_t)bt * CV + q * 8;
    f32x4 acc[4] = {};
#pragma unroll
    for (int mt = 0; mt < 4; mt++) {
        const short* ap = vb + (size_t)s_idx[wv][mt * 16 + rw] * CV + q * 8;
        f32x4 a4 = {0.f, 0.f, 0.f, 0.f};
#pragma unroll
        for (int kc = 0; kc < CV; kc += 32) {
            bf16x8 av = *(const bf16x8*)(ap + kc);
            bf16x8 bv = *(const bf16x8*)(zp + kc);
            a4 = __builtin_amdgcn_mfma_f32_16x16x32_bf16(av, bv, a4, 0, 0, 0);
        }
        acc[mt] = a4;
    }
    if (rw == 0) {   // C row m = q*4+r; all 16 cols identical, take col 0 lanes
#pragma unroll
        for (int mt = 0; mt < 4; mt++)
#pragma unroll
            for (int r = 0; r < 4; r++)
                s_ps[wv][mt * 16 + q * 4 + r] = acc[mt][r];
    }
    float p = expf((s_ps[wv][lane] + c0) * 0.03125f);
    float rs = p;
    for (int o = 32; o > 0; o >>= 1) rs += __shfl_xor(rs, o);
    s_ps[wv][lane] = p;
    if (lane == 0) ws[RS_O + bt] = rs;
    // W accum from bf16 vision rows: lane covers cv = lane*4..+3
    float4 wa = {0.f, 0.f, 0.f, 0.f};
#pragma unroll 8
    for (int s = 0; s < S; s++) {
        float pv = s_ps[wv][s];
        s16x4 r4 = *(const s16x4*)(vb + (size_t)s_idx[wv][s] * CV + lane * 4);
        wa.x += pv * bf2f(r4.x); wa.y += pv * bf2f(r4.y);
        wa.z += pv * bf2f(r4.z); wa.w += pv * bf2f(r4.w);
    }
    s16x4 o;
    o.x = f2bf(wa.x); o.y = f2bf(wa.y); o.z = f2bf(wa.z); o.w = f2bf(wa.w);
    ((s16x4*)((short*)(ws + WB_O) + (size_t)bt * CV))[lane] = o;
}

// ---- g_out: out = x + (Wb @ WvpT^T + rs*bv)/denom; denom reduced per-wave
// ---- from RS (no atomic). 256 blocks x 4 waves (1024 tiles) ----
__global__ void g_out_mfma(const float* __restrict__ x, float* __restrict__ ws,
                           float* __restrict__ out) {
    int w = blockIdx.x * 4 + (threadIdx.x >> 6);
    int m0 = (w >> 5) * 32, n0 = (w & 31) * 32;    // m: bt(1024), n: d(1024)
    int lane = threadIdx.x & 63;
    // denom for batch b = m0>>8: sum RS[b*256 .. +255]
    int b = m0 >> 8;
    float4 r4 = *(const float4*)(ws + RS_O + b * 256 + lane * 4);
    float dn = r4.x + r4.y + r4.z + r4.w;
    for (int o = 32; o > 0; o >>= 1) dn += __shfl_xor(dn, o);
    float inv = 1.0f / dn;
    const short* A = (const short*)(ws + WB_O) + (size_t)m0 * CV;
    const short* Bt = (const short*)(ws + WVPT_O) + (size_t)n0 * CV;
    f32x4 acc[2][2] = {};
    wave_mma<CV, CV, CV>(A, Bt, acc);
    int col = lane & 15, q = lane >> 4;
#pragma unroll
    for (int i = 0; i < 2; i++)
#pragma unroll
        for (int r = 0; r < 4; r++) {
            int row = m0 + i * 16 + q * 4 + r;
            float rs = ws[RS_O + row];
#pragma unroll
            for (int j = 0; j < 2; j++) {
                int cc = n0 + j * 16 + col;
                out[(size_t)row * DIM + cc] =
                    x[(size_t)row * DIM + cc] +
                    (acc[i][j][r] + rs * ws[BV_O + cc]) * inv;
            }
        }
}

extern "C" void kernel_launch(void* const* d_in, const int* in_sizes, int n_in,
                              void* d_out, int out_size, void* d_ws, size_t ws_size,
                              hipStream_t stream) {
    (void)in_sizes; (void)n_in; (void)out_size; (void)ws_size;
    const float* x      = (const float*)d_in[0];
    const float* vision = (const float*)d_in[1];
    const void*  mask   = d_in[2];
    const float* Wu     = (const float*)d_in[3];
    const float* bu     = (const float*)d_in[4];
    const float* Wk     = (const float*)d_in[5];
    const float* Wv     = (const float*)d_in[6];
    float* out = (float*)d_out;
    float* ws  = (float*)d_ws;
    int*   wsi = (int*)d_ws;

    stage1<<<2880, 256, 0, stream>>>(vision, Wu, x, Wk, Wv, bu, mask, ws, wsi);
    g_prep_mfma<<<130, 256, 0, stream>>>(ws);
    g_z_mfma<<<64, 256, 0, stream>>>(ws);
    g_attn<<<256, 256, 0, stream>>>(x, ws, wsi);
    g_out_mfma<<<256, 256, 0, stream>>>(x, ws, out);
}